// Round 19
// baseline (370.019 us; speedup 1.0000x reference)
//
#include <hip/hip_runtime.h>
#include <hip/hip_bf16.h>
#include <math.h>

// MoE top-2 of 8 experts. D_MODEL=1024, D_FF=4096, tokens = 2*2048 = 4096.
// R18: gemm1 ported to the 8-phase 256x256 schedule (m201 template, plain HIP):
// BK=64, 8 waves, 128KB dbuf LDS, per-phase {issue half-tile || 16 MFMA ||
// raw s_barrier}, counted vmcnt(2) once per K-tile (never drain mid-loop),
// G4-style XOR swizzle (both-sides), setprio around MFMA (T5, 8-phase regime).
// gemm2_y stays at R8 config (its 8192x1024 output = only 128 tiles of 256^2
// -> half the machine idle; 128^2 is right for it). Everything else = R17.

#define D_MODEL 1024
#define D_FF    4096
#define NE      8
#define NTOK    4096
#define CAP     4096

typedef __attribute__((ext_vector_type(4))) float f32x4;
typedef __attribute__((ext_vector_type(4))) short s16x4;
typedef __attribute__((ext_vector_type(8))) short s16x8;

__device__ __forceinline__ short f2bf(float f) {
    union { float f; unsigned u; } v; v.f = f;
    unsigned r = v.u + 0x7FFFu + ((v.u >> 16) & 1u);  // RNE
    return (short)(r >> 16);
}

// tanh-form gelu, ~9 VALU ops. |err| ~3e-4 << bf16 rounding.
__device__ __forceinline__ float gelu_f(float x) {
    float u = x * x;
    float v = __builtin_fmaf(0.044715f, u, 1.0f);
    float y2 = 1.5957691216057308f * x * v;
    float r = __builtin_amdgcn_rcpf(__expf(y2) + 1.0f);
    return x - x * r;
}

// async global -> LDS, 16 bytes/lane; LDS dest wave-uniform base (m104/m108).
__device__ __forceinline__ void gload16(const void* g, void* l) {
    __builtin_amdgcn_global_load_lds(
        (const __attribute__((address_space(1))) unsigned*)g,
        (__attribute__((address_space(3))) unsigned*)l, 16, 0, 0);
}

#define FENCE asm volatile("" ::: "memory")
#define BARRIER do { FENCE; __builtin_amdgcn_s_barrier(); FENCE; } while (0)

// =============== device bodies shared by fused / standalone kernels ===============

struct RouterSmem { float gw[NE][D_MODEL]; float us[NE]; };

__device__ void router_body(
    const float* __restrict__ x, const float* __restrict__ gw,
    const float* __restrict__ gb, float* __restrict__ usage,
    int* __restrict__ eidx, float* __restrict__ wgt, short* __restrict__ xb,
    RouterSmem* sm, int rb, int nblk)
{
    int tid = threadIdx.x;
    for (int i = tid * 4; i < NE * D_MODEL; i += 256 * 4)
        *(f32x4*)&sm->gw[0][i] = *(const f32x4*)(gw + i);
    if (tid < NE) sm->us[tid] = 0.f;
    __syncthreads();

    int wid = tid >> 6, lane = tid & 63;
    int wave_stride = nblk * 4;
    float l_usage[NE];
#pragma unroll
    for (int e = 0; e < NE; e++) l_usage[e] = 0.f;

    for (int t = rb * 4 + wid; t < NTOK; t += wave_stride) {
        const float* xr = x + (size_t)t * D_MODEL;
        short* xbr = xb + (size_t)t * D_MODEL;
        float acc[NE];
#pragma unroll
        for (int e = 0; e < NE; e++) acc[e] = 0.f;
        for (int i = lane * 4; i < D_MODEL; i += 64 * 4) {
            f32x4 xv = *(const f32x4*)(xr + i);
            s16x4 bv;
#pragma unroll
            for (int j = 0; j < 4; j++) bv[j] = f2bf(xv[j]);
            *(s16x4*)(xbr + i) = bv;          // fused x -> bf16
#pragma unroll
            for (int e = 0; e < NE; e++) {
                f32x4 gv = *(const f32x4*)&sm->gw[e][i];
                acc[e] += xv[0]*gv[0] + xv[1]*gv[1] + xv[2]*gv[2] + xv[3]*gv[3];
            }
        }
#pragma unroll
        for (int e = 0; e < NE; e++) {
            float a = acc[e];
            for (int off = 32; off; off >>= 1) a += __shfl_down(a, off);
            acc[e] = a;
        }
        if (lane == 0) {
            float logits[NE];
            float mx = -1e30f;
#pragma unroll
            for (int e = 0; e < NE; e++) { logits[e] = acc[e] + gb[e]; mx = fmaxf(mx, logits[e]); }
            float se = 0.f;
            float pe[NE];
#pragma unroll
            for (int e = 0; e < NE; e++) { pe[e] = expf(logits[e] - mx); se += pe[e]; }
            float inv = 1.f / se;
#pragma unroll
            for (int e = 0; e < NE; e++) l_usage[e] += pe[e] * inv;
            int i0 = 0;
#pragma unroll
            for (int e = 1; e < NE; e++) if (logits[e] > logits[i0]) i0 = e;
            int i1 = -1;
#pragma unroll
            for (int e = 0; e < NE; e++) {
                if (e == i0) continue;
                if (i1 < 0 || logits[e] > logits[i1]) i1 = e;
            }
            float w0 = 1.f / (1.f + expf(logits[i1] - logits[i0]));
            eidx[t] = i0 | (i1 << 8);
            wgt[t] = w0;
        }
    }
    if (lane == 0) {
#pragma unroll
        for (int e = 0; e < NE; e++) atomicAdd(&sm->us[e], l_usage[e]);
    }
    __syncthreads();
    if (tid < NE) atomicAdd(&usage[tid], sm->us[tid]);
}

__device__ void transpose_body(
    const float* __restrict__ src, short* __restrict__ dst, int R, int C,
    int bx, int by, int e, float (*tile)[65])
{
    src += (size_t)e * R * C;
    dst += (size_t)e * R * C;
    int c0 = bx * 64, r0 = by * 64;
    int tid = threadIdx.x;
    int lr = tid >> 2, lc = (tid & 3) * 16;

    const float* s = src + (size_t)(r0 + lr) * C + c0 + lc;
#pragma unroll
    for (int j = 0; j < 4; j++)
        *(f32x4*)&tile[lr][lc + j * 4] = *(const f32x4*)(s + j * 4);
    __syncthreads();

    short* d = dst + (size_t)(c0 + lr) * R + r0 + lc;
    s16x8 v0, v1;
#pragma unroll
    for (int j = 0; j < 8; j++) v0[j] = f2bf(tile[lc + j][lr]);
#pragma unroll
    for (int j = 0; j < 8; j++) v1[j] = f2bf(tile[lc + 8 + j][lr]);
    *(s16x8*)d = v0;
    *(s16x8*)(d + 8) = v1;
}

// =============== fused prep: router || W1-transpose || W2-transpose ===============
__global__ __launch_bounds__(256) void prep_kernel(
    const float* __restrict__ x, const float* __restrict__ gw,
    const float* __restrict__ gb, float* __restrict__ usage,
    int* __restrict__ eidx, float* __restrict__ wgt, short* __restrict__ xb,
    const float* __restrict__ w1, short* __restrict__ w1t,
    const float* __restrict__ w2, short* __restrict__ w2t)
{
    __shared__ union { RouterSmem r; float tile[64][65]; } sm;
    int b = blockIdx.x;
    if (b < 256) {
        router_body(x, gw, gb, usage, eidx, wgt, xb, &sm.r, b, 256);
    } else if (b < 256 + 8192) {
        int q = b - 256;                         // W1: grid (64,16,8)
        transpose_body(w1, w1t, D_MODEL, D_FF, q & 63, (q >> 6) & 15, q >> 10, sm.tile);
    } else {
        int q = b - 256 - 8192;                  // W2: grid (16,64,8)
        transpose_body(w2, w2t, D_FF, D_MODEL, q & 15, (q >> 4) & 63, q >> 10, sm.tile);
    }
}

// standalone router (fallback path)
__global__ __launch_bounds__(256) void router_kernel(
    const float* __restrict__ x, const float* __restrict__ gw,
    const float* __restrict__ gb, float* __restrict__ usage,
    int* __restrict__ eidx, float* __restrict__ wgt, short* __restrict__ xb)
{
    __shared__ RouterSmem sm;
    router_body(x, gw, gb, usage, eidx, wgt, xb, &sm, blockIdx.x, gridDim.x);
}

// standalone transpose (fallback path)
__global__ __launch_bounds__(256) void transpose_cvt(
    const float* __restrict__ src, short* __restrict__ dst, int R, int C)
{
    __shared__ float tile[64][65];
    transpose_body(src, dst, R, C, blockIdx.x, blockIdx.y, blockIdx.z, tile);
}

// ---------------- list compaction + fused offsets (+ optional loss) ----------------
__global__ __launch_bounds__(256) void build_lists(
    const int* __restrict__ eidx, const float* __restrict__ wgt,
    int* __restrict__ cnt, int* __restrict__ tok_list, float* __restrict__ wt_list,
    int* __restrict__ tok2slot, float* __restrict__ wgt_p,
    int* __restrict__ done, int* __restrict__ offsets,
    const float* __restrict__ usage, float* __restrict__ out_loss)
{
    int e = blockIdx.x;
    __shared__ int s_cnt;
    if (threadIdx.x == 0) s_cnt = 0;
    __syncthreads();
    for (int t = threadIdx.x; t < NTOK; t += 256) {
        int p = eidx[t];
        float w0 = wgt[t];
        if (e == 0) wgt_p[t] = w0;
        if ((p & 255) == e) {
            int s = atomicAdd(&s_cnt, 1);
            tok_list[e * CAP + s] = t; wt_list[e * CAP + s] = w0;
            tok2slot[2 * t] = (e << 16) | s;
        }
        if ((p >> 8) == e) {
            int s = atomicAdd(&s_cnt, 1);
            tok_list[e * CAP + s] = t; wt_list[e * CAP + s] = 1.f - w0;
            tok2slot[2 * t + 1] = (e << 16) | s;
        }
    }
    __syncthreads();
    if (threadIdx.x == 0) {
        cnt[e] = s_cnt;
        __threadfence();
        if (atomicAdd(done, 1) == NE - 1) {
            __threadfence();
            int o = 0;
            for (int k = 0; k < NE; k++) { offsets[k] = o; o += cnt[k]; }
            if (out_loss) {
                float s = 0.f;
                for (int k = 0; k < NE; k++) { float u = usage[k] / (float)NTOK; s += u * u; }
                *out_loss = (float)NE * s - 1.f;
            }
        }
    }
}

// ---------------- load-balancing loss (fallback: after memset) ----------------
__global__ void write_loss(const float* __restrict__ usage, float* __restrict__ out_loss)
{
    float s = 0.f;
    for (int e = 0; e < NE; e++) { float u = usage[e] / (float)NTOK; s += u * u; }
    *out_loss = (float)NE * s - 1.f;
}

// ======================= GEMM1: 8-phase 256x256, BK=64 =======================
// 512 threads = 8 waves (2M x 4N); per-wave output 128x64; acc[8][4].
// LDS [2][256][64] bf16 per operand (128KB). Swizzle: LDS(row,cc8) holds
// global(row, cc8 ^ (row&7)); read chunk (s*4+kgr)^(lrow&7).
// Per K-tile: 4 phases {issue half-tile prefetch; 16 MFMA; s_barrier};
// vmcnt(2) once per K-tile (prev tile landed, newest half in flight).
__global__ __launch_bounds__(512, 2) void gemm1_kernel(
    const short* __restrict__ XB, const short* __restrict__ W1T,
    const float* __restrict__ b1, const int* __restrict__ cnt,
    const int* __restrict__ offsets, const int* __restrict__ tok_list,
    short* __restrict__ H)
{
    // grid 2048 = 16 n-tiles x (8 experts x 16 m-tiles); XCD chunk = 256
    int r = blockIdx.x;
    int s = (r & 7) * 256 + (r >> 3);
    int bx = s & 15;                 // n-tile (fastest)
    int by = s >> 4;                 // 0..127
    int e  = by >> 4;
    int tm = by & 15;
    int ce = cnt[e];
    if (tm * 256 >= ce) return;
    int n0 = bx * 256;

    __shared__ __align__(16) short As[2][256][64];   // 64KB
    __shared__ __align__(16) short Bs[2][256][64];   // 64KB

    int tid = threadIdx.x;
    int lane = tid & 63, w64 = tid >> 6;
    int wr = w64 >> 2, wc = w64 & 3;         // 2M x 4N waves
    int lrow = lane & 15, kgr = lane >> 4;

    // staging geometry: issue j of half h: lane writes LDS row h*128+j*64+w64*8+(lane>>3),
    // chunk (lane&7); source chunk gc = (lane&7)^(lane>>3).
    int gc = (lane & 7) ^ (lane >> 3);
    const short* apt[4];
    const short* bpt[4];
#pragma unroll
    for (int h = 0; h < 2; h++) {
#pragma unroll
        for (int j = 0; j < 2; j++) {
            int rw = h * 128 + j * 64 + w64 * 8 + (lane >> 3);
            int am = tm * 256 + rw;
            int tok = tok_list[e * CAP + (am < ce ? am : 0)];
            apt[h * 2 + j] = XB + (size_t)tok * D_MODEL + gc * 8;
            bpt[h * 2 + j] = W1T + ((size_t)e * D_FF + n0 + rw) * D_MODEL + gc * 8;
        }
    }

#define ISSUE_A(NB, HH, KT)                                                    \
    gload16(apt[(HH)*2+0] + (KT), (char*)&As[NB][(HH)*128][0] + w64*1024);     \
    gload16(apt[(HH)*2+1] + (KT), (char*)&As[NB][(HH)*128][0] + 8192 + w64*1024);
#define ISSUE_B(NB, HH, KT)                                                    \
    gload16(bpt[(HH)*2+0] + (KT), (char*)&Bs[NB][(HH)*128][0] + w64*1024);     \
    gload16(bpt[(HH)*2+1] + (KT), (char*)&Bs[NB][(HH)*128][0] + 8192 + w64*1024);

#define PHASE_MFMA(BUF, S, MH)                                                 \
    {                                                                          \
        s16x8 a[4], b[4];                                                      \
        int cc = (((S) * 4 + kgr) ^ (lrow & 7)) * 8;                           \
        _Pragma("unroll")                                                      \
        for (int j2 = 0; j2 < 4; j2++)                                         \
            b[j2] = *(const s16x8*)&Bs[BUF][wc * 64 + j2 * 16 + lrow][cc];     \
        _Pragma("unroll")                                                      \
        for (int i2 = 0; i2 < 4; i2++)                                         \
            a[i2] = *(const s16x8*)&As[BUF][wr * 128 + ((MH)*4+i2)*16 + lrow][cc]; \
        __builtin_amdgcn_s_setprio(1);                                         \
        _Pragma("unroll")                                                      \
        for (int i2 = 0; i2 < 4; i2++)                                         \
            _Pragma("unroll")                                                  \
            for (int j2 = 0; j2 < 4; j2++)                                     \
                acc[(MH)*4+i2][j2] = __builtin_amdgcn_mfma_f32_16x16x32_bf16(  \
                    a[i2], b[j2], acc[(MH)*4+i2][j2], 0, 0, 0);                \
        __builtin_amdgcn_s_setprio(0);                                         \
    }

    f32x4 acc[8][4] = {};

    // prologue: stage tile 0 into buf 0 (8 gloads/thread)
    ISSUE_A(0, 0, 0); ISSUE_A(0, 1, 0); ISSUE_B(0, 0, 0); ISSUE_B(0, 1, 0);

    const int NT = D_MODEL / 64;   // 16 K-tiles
    for (int T = 0; T < NT; T++) {
        int buf = T & 1, nb = buf ^ 1;
        int ktn = (T + 1) * 64;
        bool more = (T + 1) < NT;
        if (more) { ISSUE_A(nb, 0, ktn); }
        if (more) { asm volatile("s_waitcnt vmcnt(2)" ::: "memory"); }
        else      { asm volatile("s_waitcnt vmcnt(0)" ::: "memory"); }
        BARRIER;
        PHASE_MFMA(buf, 0, 0);
        BARRIER;
        if (more) { ISSUE_A(nb, 1, ktn); }
        PHASE_MFMA(buf, 0, 1);
        BARRIER;
        if (more) { ISSUE_B(nb, 0, ktn); }
        PHASE_MFMA(buf, 1, 0);
        BARRIER;
        if (more) { ISSUE_B(nb, 1, ktn); }
        PHASE_MFMA(buf, 1, 1);
        BARRIER;
    }

    int offe = offsets[e];
    float bn[4];
#pragma unroll
    for (int j = 0; j < 4; j++) bn[j] = b1[e * D_FF + n0 + wc * 64 + j * 16 + lrow];
#pragma unroll
    for (int i = 0; i < 8; i++) {
#pragma unroll
        for (int q = 0; q < 4; q++) {
            int m = tm * 256 + wr * 128 + i * 16 + kgr * 4 + q;
            if (m >= ce) continue;
            short* hrow = H + (size_t)(offe + m) * D_FF;
#pragma unroll
            for (int j = 0; j < 4; j++) {
                int n = n0 + wc * 64 + j * 16 + lrow;
                hrow[n] = f2bf(gelu_f(acc[i][j][q] + bn[j]));
            }
        }
    }
#undef ISSUE_A
#undef ISSUE_B
#undef PHASE_MFMA
}

// Shared GEMM K-step pieces for gemm2 (BK=32, single buffer -- R8 proven).
#define GEMM_STAGE(AS, BS, KT)                       \
    gload16(asrc0 + (KT), &AS[wid * 16][0]);         \
    gload16(asrc1 + (KT), &AS[64 + wid * 16][0]);    \
    gload16(bsrc0 + (KT), &BS[wid * 16][0]);         \
    gload16(bsrc1 + (KT), &BS[64 + wid * 16][0]);

#define GEMM_COMPUTE(AS, BS)                                                   \
    {                                                                          \
        s16x8 a[4], b[4];                                                      \
        int cidx = (kgr ^ ((lrow >> 1) & 3)) * 8;                              \
        _Pragma("unroll")                                                      \
        for (int i = 0; i < 4; i++) {                                          \
            a[i] = *(const s16x8*)&AS[wr * 64 + i * 16 + lrow][cidx];          \
            b[i] = *(const s16x8*)&BS[wc * 64 + i * 16 + lrow][cidx];          \
        }                                                                      \
        _Pragma("unroll")                                                      \
        for (int i = 0; i < 4; i++)                                            \
            _Pragma("unroll")                                                  \
            for (int j = 0; j < 4; j++)                                        \
                acc[i][j] = __builtin_amdgcn_mfma_f32_16x16x32_bf16(           \
                    a[i], b[j], acc[i][j], 0, 0, 0);                           \
    }

// ---------------- GEMM2-Y: Y[slot] = H[slot] @ W2[e] + b2[e], 128x128, BK=32 ----------------
__global__ __launch_bounds__(256) void gemm2_y_kernel(
    const short* __restrict__ H, const short* __restrict__ W2T,
    const float* __restrict__ b2, const int* __restrict__ cnt,
    const int* __restrict__ offsets, float* __restrict__ Y)
{
    int r = blockIdx.x;
    int s = (r & 7) * 256 + (r >> 3);
    int bx = s & 7;
    int by = s >> 3;
    int e  = by >> 5;
    int tm = by & 31;
    int ce = cnt[e];
    if (tm * 128 >= ce) return;
    int offe = offsets[e];
    int n0 = bx * 128;

    __shared__ __align__(16) short As[128][32];
    __shared__ __align__(16) short Bs[128][32];

    int tid = threadIdx.x;
    int lane = tid & 63, wid = tid >> 6;
    int wr = wid >> 1, wc = wid & 1;
    int lrow = lane & 15, kgr = lane >> 4;

    int srow = wid * 16 + (lane >> 2);
    int scol = ((lane & 3) ^ ((lane >> 3) & 3)) * 8;
    int am0 = tm * 128 + srow, am1 = am0 + 64;
    const short* asrc0 = H + (size_t)(offe + (am0 < ce ? am0 : 0)) * D_FF + scol;
    const short* asrc1 = H + (size_t)(offe + (am1 < ce ? am1 : 0)) * D_FF + scol;
    const short* bsrc0 = W2T + ((size_t)e * D_MODEL + n0 + srow) * D_FF + scol;
    const short* bsrc1 = bsrc0 + (size_t)64 * D_FF;

    f32x4 acc[4][4] = {};
    for (int kt = 0; kt < D_FF; kt += 32) {
        GEMM_STAGE(As, Bs, kt);
        __syncthreads();
        GEMM_COMPUTE(As, Bs);
        __syncthreads();
    }

    float bn[4];
#pragma unroll
    for (int j = 0; j < 4; j++) bn[j] = b2[e * D_MODEL + n0 + wc * 64 + j * 16 + lrow];
#pragma unroll
    for (int i = 0; i < 4; i++) {
#pragma unroll
        for (int q = 0; q < 4; q++) {
            int m = tm * 128 + wr * 64 + i * 16 + kgr * 4 + q;
            if (m >= ce) continue;
            float* yrow = Y + (size_t)(offe + m) * D_MODEL;
#pragma unroll
            for (int j = 0; j < 4; j++) {
                int n = n0 + wc * 64 + j * 16 + lrow;
                yrow[n] = acc[i][j][q] + bn[j];
            }
        }
    }
}

// ---------------- combine: out[t] = w0*Y[slot0] + w1*Y[slot1] ----------------
__global__ __launch_bounds__(256) void combine_kernel(
    const float* __restrict__ Y, const int* __restrict__ tok2slot,
    const float* __restrict__ wgt_p, const int* __restrict__ offsets,
    float* __restrict__ out)
{
    int t = blockIdx.x;
    int d = threadIdx.x * 4;
    int p0 = tok2slot[2 * t], p1 = tok2slot[2 * t + 1];
    int s0 = offsets[p0 >> 16] + (p0 & 0xFFFF);
    int s1 = offsets[p1 >> 16] + (p1 & 0xFFFF);
    float w0 = wgt_p[t], w1 = 1.f - w0;
    f32x4 a = *(const f32x4*)(Y + (size_t)s0 * D_MODEL + d);
    f32x4 b = *(const f32x4*)(Y + (size_t)s1 * D_MODEL + d);
    f32x4 r;
#pragma unroll
    for (int j = 0; j < 4; j++) r[j] = w0 * a[j] + w1 * b[j];
    *(f32x4*)(out + (size_t)t * D_MODEL + d) = r;
}

// ---------------- GEMM2 atomic fallback (split-K=2, BK=32) ----------------
__global__ __launch_bounds__(256) void gemm2_kernel(
    const short* __restrict__ H, const short* __restrict__ W2T,
    const float* __restrict__ b2, const int* __restrict__ cnt,
    const int* __restrict__ offsets, const int* __restrict__ tok_list,
    const float* __restrict__ wt_list, float* __restrict__ out)
{
    int e  = blockIdx.y >> 5;
    int tm = blockIdx.y & 31;
    int ce = cnt[e];
    if (tm * 128 >= ce) return;
    int offe = offsets[e];
    int n0 = blockIdx.x * 128;
    int kz = blockIdx.z;
    const int KSPAN = D_FF / 2;
    int kbase = kz * KSPAN;

    __shared__ __align__(16) short As[128][32];
    __shared__ __align__(16) short Bs[128][32];

    int tid = threadIdx.x;
    int lane = tid & 63, wid = tid >> 6;
    int wr = wid >> 1, wc = wid & 1;
    int lrow = lane & 15, kgr = lane >> 4;

    int srow = wid * 16 + (lane >> 2);
    int scol = ((lane & 3) ^ ((lane >> 3) & 3)) * 8;
    int am0 = tm * 128 + srow, am1 = am0 + 64;
    const short* asrc0 = H + (size_t)(offe + (am0 < ce ? am0 : 0)) * D_FF + kbase + scol;
    const short* asrc1 = H + (size_t)(offe + (am1 < ce ? am1 : 0)) * D_FF + kbase + scol;
    const short* bsrc0 = W2T + ((size_t)e * D_MODEL + n0 + srow) * D_FF + kbase + scol;
    const short* bsrc1 = bsrc0 + (size_t)64 * D_FF;

    f32x4 acc[4][4] = {};
    for (int kt = 0; kt < KSPAN; kt += 32) {
        GEMM_STAGE(As, Bs, kt);
        __syncthreads();
        GEMM_COMPUTE(As, Bs);
        __syncthreads();
    }

    float bn[4];
#pragma unroll
    for (int j = 0; j < 4; j++)
        bn[j] = (kz == 0) ? b2[e * D_MODEL + n0 + wc * 64 + j * 16 + lrow] : 0.f;
#pragma unroll
    for (int i = 0; i < 4; i++) {
#pragma unroll
        for (int q = 0; q < 4; q++) {
            int m = tm * 128 + wr * 64 + i * 16 + kgr * 4 + q;
            if (m >= ce) continue;
            int tokm = tok_list[e * CAP + m];
            float wt = wt_list[e * CAP + m];
            float* orow = out + (size_t)tokm * D_MODEL;
#pragma unroll
            for (int j = 0; j < 4; j++) {
                int n = n0 + wc * 64 + j * 16 + lrow;
                atomicAdd(&orow[n], wt * (acc[i][j][q] + bn[j]));
            }
        }
    }
}

extern "C" void kernel_launch(void* const* d_in, const int* in_sizes, int n_in,
                              void* d_out, int out_size, void* d_ws, size_t ws_size,
                              hipStream_t stream)
{
    const float* x  = (const float*)d_in[0];
    const float* gw = (const float*)d_in[1];
    const float* gb = (const float*)d_in[2];
    const float* w1 = (const float*)d_in[3];
    const float* b1 = (const float*)d_in[4];
    const float* w2 = (const float*)d_in[5];
    const float* b2 = (const float*)d_in[6];
    float* out = (float*)d_out;

    char* w = (char*)d_ws;
    int*   cnt      = (int*)(w + 0);
    float* usage    = (float*)(w + 32);
    int*   offsets  = (int*)(w + 64);
    int*   done     = (int*)(w + 96);
    int*   tok_list = (int*)(w + 128);                       // 128 KB
    float* wt_list  = (float*)(w + 128 + 131072);            // 128 KB
    int*   tok2slot = (int*)(w + 128 + 262144);              // 32 KB
    float* wgt_p    = (float*)(w + 128 + 262144 + 32768);    // 16 KB
    const size_t MB64 = 67108864ull;
    short* XB       = (short*)d_out;                         // 8MB, dead until combine
    float* out_loss = out + (size_t)NTOK * D_MODEL;

    size_t need_sep = 311424 + 3ull * MB64;                  // W1T + W2T + H
    size_t need_y1  = 311424 + 2ull * MB64 + 33554432ull;
    hipMemsetAsync(d_ws, 0, 128, stream);

    if (ws_size >= need_sep) {
        short* W1T = (short*)(w + 311424);
        short* W2T = (short*)(w + 311424 + MB64);
        short* H   = (short*)(w + 311424 + 2 * MB64);
        float* Y   = (float*)W1T;                            // W1T dead after gemm1
        int*   eidx = (int*)H;                               // H dead until gemm1
        float* wgt  = (float*)((char*)H + 16384);

        prep_kernel<<<256 + 8192 + 8192, 256, 0, stream>>>(
            x, gw, gb, usage, eidx, wgt, XB, w1, W1T, w2, W2T);
        build_lists<<<NE, 256, 0, stream>>>(
            eidx, wgt, cnt, tok_list, wt_list, tok2slot, wgt_p,
            done, offsets, usage, out_loss);
        gemm1_kernel<<<2048, 512, 0, stream>>>(
            XB, W1T, b1, cnt, offsets, tok_list, H);
        gemm2_y_kernel<<<2048, 256, 0, stream>>>(H, W2T, b2, cnt, offsets, Y);
        combine_kernel<<<NTOK, 256, 0, stream>>>(Y, tok2slot, wgt_p, offsets, out);
        return;
    }

    // fallback: sequential layout (WT reused for W1T then W2T)
    short* WT  = (short*)(w + 311424);
    short* H   = (short*)(w + 311424 + MB64);
    float* Y   = (float*)(w + 311424 + 2 * MB64);
    bool   use_y = ws_size >= need_y1;
    int*   eidx = (int*)WT;
    float* wgt  = (float*)(WT + NTOK * 2);

    router_kernel<<<256, 256, 0, stream>>>(x, gw, gb, usage, eidx, wgt, XB);
    build_lists<<<NE, 256, 0, stream>>>(
        eidx, wgt, cnt, tok_list, wt_list, tok2slot, wgt_p,
        done, offsets, usage, nullptr);

    transpose_cvt<<<dim3(D_FF / 64, D_MODEL / 64, NE), 256, 0, stream>>>(w1, WT, D_MODEL, D_FF);
    gemm1_kernel<<<2048, 512, 0, stream>>>(XB, WT, b1, cnt, offsets, tok_list, H);
    transpose_cvt<<<dim3(D_MODEL / 64, D_FF / 64, NE), 256, 0, stream>>>(w2, WT, D_FF, D_MODEL);

    if (use_y) {
        write_loss<<<1, 1, 0, stream>>>(usage, out_loss);
        gemm2_y_kernel<<<2048, 256, 0, stream>>>(H, WT, b2, cnt, offsets, Y);
        combine_kernel<<<NTOK, 256, 0, stream>>>(Y, tok2slot, wgt_p, offsets, out);
    } else {
        hipMemsetAsync(d_out, 0, (size_t)out_size * sizeof(float), stream);
        write_loss<<<1, 1, 0, stream>>>(usage, out_loss);
        gemm2_kernel<<<dim3(D_MODEL / 128, NE * (CAP / 128), 2), 256, 0, stream>>>(
            H, WT, b2, cnt, offsets, tok_list, wt_list, out);
    }
}

// Round 20
// 315.819 us; speedup vs baseline: 1.1716x; 1.1716x over previous
//
#include <hip/hip_runtime.h>
#include <hip/hip_bf16.h>
#include <math.h>

// MoE top-2 of 8 experts. D_MODEL=1024, D_FF=4096, tokens = 2*2048 = 4096.
// R19: final revert to R15/R17 config (best measured: 315.96us, reproduced).
// R18's 8-phase 256^2 port regressed (199us gemm1): 128KB LDS -> 1 block/CU,
// and the 4-phase approximation doesn't reproduce m201's derived-wait overlap
// (consistent with m232's 128^2+8ph null). Terminal state: prep at HBM
// roofline; GEMMs at the 2-barrier 128^2 structural ceiling (~515TF, 8
// schedule variants A/B-tested worse); atomics eliminated; fixed costs fused.

#define D_MODEL 1024
#define D_FF    4096
#define NE      8
#define NTOK    4096
#define CAP     4096

typedef __attribute__((ext_vector_type(4))) float f32x4;
typedef __attribute__((ext_vector_type(4))) short s16x4;
typedef __attribute__((ext_vector_type(8))) short s16x8;

__device__ __forceinline__ short f2bf(float f) {
    union { float f; unsigned u; } v; v.f = f;
    unsigned r = v.u + 0x7FFFu + ((v.u >> 16) & 1u);  // RNE
    return (short)(r >> 16);
}

// tanh-form gelu, ~9 VALU ops. |err| ~3e-4 << bf16 rounding.
__device__ __forceinline__ float gelu_f(float x) {
    float u = x * x;
    float v = __builtin_fmaf(0.044715f, u, 1.0f);
    float y2 = 1.5957691216057308f * x * v;
    float r = __builtin_amdgcn_rcpf(__expf(y2) + 1.0f);
    return x - x * r;
}

// async global -> LDS, 16 bytes/lane; LDS dest wave-uniform base (m104/m108).
__device__ __forceinline__ void gload16(const void* g, void* l) {
    __builtin_amdgcn_global_load_lds(
        (const __attribute__((address_space(1))) unsigned*)g,
        (__attribute__((address_space(3))) unsigned*)l, 16, 0, 0);
}

// =============== device bodies shared by fused / standalone kernels ===============

struct RouterSmem { float gw[NE][D_MODEL]; float us[NE]; };

__device__ void router_body(
    const float* __restrict__ x, const float* __restrict__ gw,
    const float* __restrict__ gb, float* __restrict__ usage,
    int* __restrict__ eidx, float* __restrict__ wgt, short* __restrict__ xb,
    RouterSmem* sm, int rb, int nblk)
{
    int tid = threadIdx.x;
    for (int i = tid * 4; i < NE * D_MODEL; i += 256 * 4)
        *(f32x4*)&sm->gw[0][i] = *(const f32x4*)(gw + i);
    if (tid < NE) sm->us[tid] = 0.f;
    __syncthreads();

    int wid = tid >> 6, lane = tid & 63;
    int wave_stride = nblk * 4;
    float l_usage[NE];
#pragma unroll
    for (int e = 0; e < NE; e++) l_usage[e] = 0.f;

    for (int t = rb * 4 + wid; t < NTOK; t += wave_stride) {
        const float* xr = x + (size_t)t * D_MODEL;
        short* xbr = xb + (size_t)t * D_MODEL;
        float acc[NE];
#pragma unroll
        for (int e = 0; e < NE; e++) acc[e] = 0.f;
        for (int i = lane * 4; i < D_MODEL; i += 64 * 4) {
            f32x4 xv = *(const f32x4*)(xr + i);
            s16x4 bv;
#pragma unroll
            for (int j = 0; j < 4; j++) bv[j] = f2bf(xv[j]);
            *(s16x4*)(xbr + i) = bv;          // fused x -> bf16
#pragma unroll
            for (int e = 0; e < NE; e++) {
                f32x4 gv = *(const f32x4*)&sm->gw[e][i];
                acc[e] += xv[0]*gv[0] + xv[1]*gv[1] + xv[2]*gv[2] + xv[3]*gv[3];
            }
        }
#pragma unroll
        for (int e = 0; e < NE; e++) {
            float a = acc[e];
            for (int off = 32; off; off >>= 1) a += __shfl_down(a, off);
            acc[e] = a;
        }
        if (lane == 0) {
            float logits[NE];
            float mx = -1e30f;
#pragma unroll
            for (int e = 0; e < NE; e++) { logits[e] = acc[e] + gb[e]; mx = fmaxf(mx, logits[e]); }
            float se = 0.f;
            float pe[NE];
#pragma unroll
            for (int e = 0; e < NE; e++) { pe[e] = expf(logits[e] - mx); se += pe[e]; }
            float inv = 1.f / se;
#pragma unroll
            for (int e = 0; e < NE; e++) l_usage[e] += pe[e] * inv;
            int i0 = 0;
#pragma unroll
            for (int e = 1; e < NE; e++) if (logits[e] > logits[i0]) i0 = e;
            int i1 = -1;
#pragma unroll
            for (int e = 0; e < NE; e++) {
                if (e == i0) continue;
                if (i1 < 0 || logits[e] > logits[i1]) i1 = e;
            }
            float w0 = 1.f / (1.f + expf(logits[i1] - logits[i0]));
            eidx[t] = i0 | (i1 << 8);
            wgt[t] = w0;
        }
    }
    if (lane == 0) {
#pragma unroll
        for (int e = 0; e < NE; e++) atomicAdd(&sm->us[e], l_usage[e]);
    }
    __syncthreads();
    if (tid < NE) atomicAdd(&usage[tid], sm->us[tid]);
}

__device__ void transpose_body(
    const float* __restrict__ src, short* __restrict__ dst, int R, int C,
    int bx, int by, int e, float (*tile)[65])
{
    src += (size_t)e * R * C;
    dst += (size_t)e * R * C;
    int c0 = bx * 64, r0 = by * 64;
    int tid = threadIdx.x;
    int lr = tid >> 2, lc = (tid & 3) * 16;

    const float* s = src + (size_t)(r0 + lr) * C + c0 + lc;
#pragma unroll
    for (int j = 0; j < 4; j++)
        *(f32x4*)&tile[lr][lc + j * 4] = *(const f32x4*)(s + j * 4);
    __syncthreads();

    short* d = dst + (size_t)(c0 + lr) * R + r0 + lc;
    s16x8 v0, v1;
#pragma unroll
    for (int j = 0; j < 8; j++) v0[j] = f2bf(tile[lc + j][lr]);
#pragma unroll
    for (int j = 0; j < 8; j++) v1[j] = f2bf(tile[lc + 8 + j][lr]);
    *(s16x8*)d = v0;
    *(s16x8*)(d + 8) = v1;
}

// =============== fused prep: router || W1-transpose || W2-transpose ===============
__global__ __launch_bounds__(256) void prep_kernel(
    const float* __restrict__ x, const float* __restrict__ gw,
    const float* __restrict__ gb, float* __restrict__ usage,
    int* __restrict__ eidx, float* __restrict__ wgt, short* __restrict__ xb,
    const float* __restrict__ w1, short* __restrict__ w1t,
    const float* __restrict__ w2, short* __restrict__ w2t)
{
    __shared__ union { RouterSmem r; float tile[64][65]; } sm;
    int b = blockIdx.x;
    if (b < 256) {
        router_body(x, gw, gb, usage, eidx, wgt, xb, &sm.r, b, 256);
    } else if (b < 256 + 8192) {
        int q = b - 256;                         // W1: grid (64,16,8)
        transpose_body(w1, w1t, D_MODEL, D_FF, q & 63, (q >> 6) & 15, q >> 10, sm.tile);
    } else {
        int q = b - 256 - 8192;                  // W2: grid (16,64,8)
        transpose_body(w2, w2t, D_FF, D_MODEL, q & 15, (q >> 4) & 63, q >> 10, sm.tile);
    }
}

// standalone router (fallback path)
__global__ __launch_bounds__(256) void router_kernel(
    const float* __restrict__ x, const float* __restrict__ gw,
    const float* __restrict__ gb, float* __restrict__ usage,
    int* __restrict__ eidx, float* __restrict__ wgt, short* __restrict__ xb)
{
    __shared__ RouterSmem sm;
    router_body(x, gw, gb, usage, eidx, wgt, xb, &sm, blockIdx.x, gridDim.x);
}

// standalone transpose (fallback path)
__global__ __launch_bounds__(256) void transpose_cvt(
    const float* __restrict__ src, short* __restrict__ dst, int R, int C)
{
    __shared__ float tile[64][65];
    transpose_body(src, dst, R, C, blockIdx.x, blockIdx.y, blockIdx.z, tile);
}

// ---------------- list compaction + fused offsets (+ optional loss) ----------------
__global__ __launch_bounds__(256) void build_lists(
    const int* __restrict__ eidx, const float* __restrict__ wgt,
    int* __restrict__ cnt, int* __restrict__ tok_list, float* __restrict__ wt_list,
    int* __restrict__ tok2slot, float* __restrict__ wgt_p,
    int* __restrict__ done, int* __restrict__ offsets,
    const float* __restrict__ usage, float* __restrict__ out_loss)
{
    int e = blockIdx.x;
    __shared__ int s_cnt;
    if (threadIdx.x == 0) s_cnt = 0;
    __syncthreads();
    for (int t = threadIdx.x; t < NTOK; t += 256) {
        int p = eidx[t];
        float w0 = wgt[t];
        if (e == 0) wgt_p[t] = w0;
        if ((p & 255) == e) {
            int s = atomicAdd(&s_cnt, 1);
            tok_list[e * CAP + s] = t; wt_list[e * CAP + s] = w0;
            tok2slot[2 * t] = (e << 16) | s;
        }
        if ((p >> 8) == e) {
            int s = atomicAdd(&s_cnt, 1);
            tok_list[e * CAP + s] = t; wt_list[e * CAP + s] = 1.f - w0;
            tok2slot[2 * t + 1] = (e << 16) | s;
        }
    }
    __syncthreads();
    if (threadIdx.x == 0) {
        cnt[e] = s_cnt;
        __threadfence();                          // make cnt visible device-wide
        if (atomicAdd(done, 1) == NE - 1) {       // last block finalizes
            __threadfence();
            int o = 0;
            for (int k = 0; k < NE; k++) { offsets[k] = o; o += cnt[k]; }
            if (out_loss) {
                float s = 0.f;
                for (int k = 0; k < NE; k++) { float u = usage[k] / (float)NTOK; s += u * u; }
                *out_loss = (float)NE * s - 1.f;
            }
        }
    }
}

// ---------------- load-balancing loss (fallback: after memset) ----------------
__global__ void write_loss(const float* __restrict__ usage, float* __restrict__ out_loss)
{
    float s = 0.f;
    for (int e = 0; e < NE; e++) { float u = usage[e] / (float)NTOK; s += u * u; }
    *out_loss = (float)NE * s - 1.f;
}

// Shared GEMM K-step pieces (BK=32, single buffer -- R8 proven). LDS [128][32].
#define GEMM_STAGE(AS, BS, KT)                       \
    gload16(asrc0 + (KT), &AS[wid * 16][0]);         \
    gload16(asrc1 + (KT), &AS[64 + wid * 16][0]);    \
    gload16(bsrc0 + (KT), &BS[wid * 16][0]);         \
    gload16(bsrc1 + (KT), &BS[64 + wid * 16][0]);

#define GEMM_COMPUTE(AS, BS)                                                   \
    {                                                                          \
        s16x8 a[4], b[4];                                                      \
        int cidx = (kgr ^ ((lrow >> 1) & 3)) * 8;                              \
        _Pragma("unroll")                                                      \
        for (int i = 0; i < 4; i++) {                                          \
            a[i] = *(const s16x8*)&AS[wr * 64 + i * 16 + lrow][cidx];          \
            b[i] = *(const s16x8*)&BS[wc * 64 + i * 16 + lrow][cidx];          \
        }                                                                      \
        _Pragma("unroll")                                                      \
        for (int i = 0; i < 4; i++)                                            \
            _Pragma("unroll")                                                  \
            for (int j = 0; j < 4; j++)                                        \
                acc[i][j] = __builtin_amdgcn_mfma_f32_16x16x32_bf16(           \
                    a[i], b[j], acc[i][j], 0, 0, 0);                           \
    }

// ---------------- GEMM1: H = gelu(x_bf @ W1 + b1), 128x128 tile, BK=32 ----------------
__global__ __launch_bounds__(256) void gemm1_kernel(
    const short* __restrict__ XB, const short* __restrict__ W1T,
    const float* __restrict__ b1, const int* __restrict__ cnt,
    const int* __restrict__ offsets, const int* __restrict__ tok_list,
    short* __restrict__ H)
{
    int r = blockIdx.x;
    int s = (r & 7) * 1024 + (r >> 3);
    int bx = s & 31;
    int by = s >> 5;
    int e  = by >> 5;
    int tm = by & 31;
    int ce = cnt[e];
    if (tm * 128 >= ce) return;
    int n0 = bx * 128;

    __shared__ __align__(16) short As[128][32];
    __shared__ __align__(16) short Bs[128][32];

    int tid = threadIdx.x;
    int lane = tid & 63, wid = tid >> 6;
    int wr = wid >> 1, wc = wid & 1;
    int lrow = lane & 15, kgr = lane >> 4;

    int srow = wid * 16 + (lane >> 2);
    int scol = ((lane & 3) ^ ((lane >> 3) & 3)) * 8;
    int am0 = tm * 128 + srow, am1 = am0 + 64;
    int tok0 = tok_list[e * CAP + (am0 < ce ? am0 : 0)];
    int tok1 = tok_list[e * CAP + (am1 < ce ? am1 : 0)];
    const short* asrc0 = XB + (size_t)tok0 * D_MODEL + scol;
    const short* asrc1 = XB + (size_t)tok1 * D_MODEL + scol;
    const short* bsrc0 = W1T + ((size_t)e * D_FF + n0 + srow) * D_MODEL + scol;
    const short* bsrc1 = bsrc0 + (size_t)64 * D_MODEL;

    f32x4 acc[4][4] = {};
    for (int kt = 0; kt < D_MODEL; kt += 32) {
        GEMM_STAGE(As, Bs, kt);
        __syncthreads();
        GEMM_COMPUTE(As, Bs);
        __syncthreads();
    }

    int offe = offsets[e];
    float bn[4];
#pragma unroll
    for (int j = 0; j < 4; j++) bn[j] = b1[e * D_FF + n0 + wc * 64 + j * 16 + lrow];
#pragma unroll
    for (int i = 0; i < 4; i++) {
#pragma unroll
        for (int q = 0; q < 4; q++) {
            int m = tm * 128 + wr * 64 + i * 16 + kgr * 4 + q;
            if (m >= ce) continue;
            short* hrow = H + (size_t)(offe + m) * D_FF;
#pragma unroll
            for (int j = 0; j < 4; j++) {
                int n = n0 + wc * 64 + j * 16 + lrow;
                hrow[n] = f2bf(gelu_f(acc[i][j][q] + bn[j]));
            }
        }
    }
}

// ---------------- GEMM2-Y: Y[slot] = H[slot] @ W2[e] + b2[e], 128x128, BK=32 ----------------
__global__ __launch_bounds__(256) void gemm2_y_kernel(
    const short* __restrict__ H, const short* __restrict__ W2T,
    const float* __restrict__ b2, const int* __restrict__ cnt,
    const int* __restrict__ offsets, float* __restrict__ Y)
{
    int r = blockIdx.x;
    int s = (r & 7) * 256 + (r >> 3);
    int bx = s & 7;
    int by = s >> 3;
    int e  = by >> 5;
    int tm = by & 31;
    int ce = cnt[e];
    if (tm * 128 >= ce) return;
    int offe = offsets[e];
    int n0 = bx * 128;

    __shared__ __align__(16) short As[128][32];
    __shared__ __align__(16) short Bs[128][32];

    int tid = threadIdx.x;
    int lane = tid & 63, wid = tid >> 6;
    int wr = wid >> 1, wc = wid & 1;
    int lrow = lane & 15, kgr = lane >> 4;

    int srow = wid * 16 + (lane >> 2);
    int scol = ((lane & 3) ^ ((lane >> 3) & 3)) * 8;
    int am0 = tm * 128 + srow, am1 = am0 + 64;
    const short* asrc0 = H + (size_t)(offe + (am0 < ce ? am0 : 0)) * D_FF + scol;
    const short* asrc1 = H + (size_t)(offe + (am1 < ce ? am1 : 0)) * D_FF + scol;
    const short* bsrc0 = W2T + ((size_t)e * D_MODEL + n0 + srow) * D_FF + scol;
    const short* bsrc1 = bsrc0 + (size_t)64 * D_FF;

    f32x4 acc[4][4] = {};
    for (int kt = 0; kt < D_FF; kt += 32) {
        GEMM_STAGE(As, Bs, kt);
        __syncthreads();
        GEMM_COMPUTE(As, Bs);
        __syncthreads();
    }

    float bn[4];
#pragma unroll
    for (int j = 0; j < 4; j++) bn[j] = b2[e * D_MODEL + n0 + wc * 64 + j * 16 + lrow];
#pragma unroll
    for (int i = 0; i < 4; i++) {
#pragma unroll
        for (int q = 0; q < 4; q++) {
            int m = tm * 128 + wr * 64 + i * 16 + kgr * 4 + q;
            if (m >= ce) continue;
            float* yrow = Y + (size_t)(offe + m) * D_MODEL;
#pragma unroll
            for (int j = 0; j < 4; j++) {
                int n = n0 + wc * 64 + j * 16 + lrow;
                yrow[n] = acc[i][j][q] + bn[j];
            }
        }
    }
}

// ---------------- combine: out[t] = w0*Y[slot0] + w1*Y[slot1] ----------------
__global__ __launch_bounds__(256) void combine_kernel(
    const float* __restrict__ Y, const int* __restrict__ tok2slot,
    const float* __restrict__ wgt_p, const int* __restrict__ offsets,
    float* __restrict__ out)
{
    int t = blockIdx.x;
    int d = threadIdx.x * 4;
    int p0 = tok2slot[2 * t], p1 = tok2slot[2 * t + 1];
    int s0 = offsets[p0 >> 16] + (p0 & 0xFFFF);
    int s1 = offsets[p1 >> 16] + (p1 & 0xFFFF);
    float w0 = wgt_p[t], w1 = 1.f - w0;
    f32x4 a = *(const f32x4*)(Y + (size_t)s0 * D_MODEL + d);
    f32x4 b = *(const f32x4*)(Y + (size_t)s1 * D_MODEL + d);
    f32x4 r;
#pragma unroll
    for (int j = 0; j < 4; j++) r[j] = w0 * a[j] + w1 * b[j];
    *(f32x4*)(out + (size_t)t * D_MODEL + d) = r;
}

// ---------------- GEMM2 atomic fallback (split-K=2, BK=32) ----------------
__global__ __launch_bounds__(256) void gemm2_kernel(
    const short* __restrict__ H, const short* __restrict__ W2T,
    const float* __restrict__ b2, const int* __restrict__ cnt,
    const int* __restrict__ offsets, const int* __restrict__ tok_list,
    const float* __restrict__ wt_list, float* __restrict__ out)
{
    int e  = blockIdx.y >> 5;
    int tm = blockIdx.y & 31;
    int ce = cnt[e];
    if (tm * 128 >= ce) return;
    int offe = offsets[e];
    int n0 = blockIdx.x * 128;
    int kz = blockIdx.z;
    const int KSPAN = D_FF / 2;
    int kbase = kz * KSPAN;

    __shared__ __align__(16) short As[128][32];
    __shared__ __align__(16) short Bs[128][32];

    int tid = threadIdx.x;
    int lane = tid & 63, wid = tid >> 6;
    int wr = wid >> 1, wc = wid & 1;
    int lrow = lane & 15, kgr = lane >> 4;

    int srow = wid * 16 + (lane >> 2);
    int scol = ((lane & 3) ^ ((lane >> 3) & 3)) * 8;
    int am0 = tm * 128 + srow, am1 = am0 + 64;
    const short* asrc0 = H + (size_t)(offe + (am0 < ce ? am0 : 0)) * D_FF + kbase + scol;
    const short* asrc1 = H + (size_t)(offe + (am1 < ce ? am1 : 0)) * D_FF + kbase + scol;
    const short* bsrc0 = W2T + ((size_t)e * D_MODEL + n0 + srow) * D_FF + kbase + scol;
    const short* bsrc1 = bsrc0 + (size_t)64 * D_FF;

    f32x4 acc[4][4] = {};
    for (int kt = 0; kt < KSPAN; kt += 32) {
        GEMM_STAGE(As, Bs, kt);
        __syncthreads();
        GEMM_COMPUTE(As, Bs);
        __syncthreads();
    }

    float bn[4];
#pragma unroll
    for (int j = 0; j < 4; j++)
        bn[j] = (kz == 0) ? b2[e * D_MODEL + n0 + wc * 64 + j * 16 + lrow] : 0.f;
#pragma unroll
    for (int i = 0; i < 4; i++) {
#pragma unroll
        for (int q = 0; q < 4; q++) {
            int m = tm * 128 + wr * 64 + i * 16 + kgr * 4 + q;
            if (m >= ce) continue;
            int tokm = tok_list[e * CAP + m];
            float wt = wt_list[e * CAP + m];
            float* orow = out + (size_t)tokm * D_MODEL;
#pragma unroll
            for (int j = 0; j < 4; j++) {
                int n = n0 + wc * 64 + j * 16 + lrow;
                atomicAdd(&orow[n], wt * (acc[i][j][q] + bn[j]));
            }
        }
    }
}

extern "C" void kernel_launch(void* const* d_in, const int* in_sizes, int n_in,
                              void* d_out, int out_size, void* d_ws, size_t ws_size,
                              hipStream_t stream)
{
    const float* x  = (const float*)d_in[0];
    const float* gw = (const float*)d_in[1];
    const float* gb = (const float*)d_in[2];
    const float* w1 = (const float*)d_in[3];
    const float* b1 = (const float*)d_in[4];
    const float* w2 = (const float*)d_in[5];
    const float* b2 = (const float*)d_in[6];
    float* out = (float*)d_out;

    // common small region (311424 B)
    char* w = (char*)d_ws;
    int*   cnt      = (int*)(w + 0);
    float* usage    = (float*)(w + 32);
    int*   offsets  = (int*)(w + 64);
    int*   done     = (int*)(w + 96);
    int*   tok_list = (int*)(w + 128);                       // 128 KB
    float* wt_list  = (float*)(w + 128 + 131072);            // 128 KB
    int*   tok2slot = (int*)(w + 128 + 262144);              // 32 KB
    float* wgt_p    = (float*)(w + 128 + 262144 + 32768);    // 16 KB
    const size_t MB64 = 67108864ull;
    short* XB       = (short*)d_out;                         // 8MB, dead until combine
    float* out_loss = out + (size_t)NTOK * D_MODEL;          // outside XB (16MB offset)

    size_t need_sep = 311424 + 3ull * MB64;                  // W1T + W2T + H (192.3MB, proven)
    size_t need_y1  = 311424 + 2ull * MB64 + 33554432ull;
    hipMemsetAsync(d_ws, 0, 128, stream);                    // cnt/usage/offsets/done

    if (ws_size >= need_sep) {
        // overlap path: separate W1T/W2T; Y aliases dead W1T
        short* W1T = (short*)(w + 311424);
        short* W2T = (short*)(w + 311424 + MB64);
        short* H   = (short*)(w + 311424 + 2 * MB64);
        float* Y   = (float*)W1T;                            // W1T dead after gemm1
        int*   eidx = (int*)H;                               // H dead until gemm1
        float* wgt  = (float*)((char*)H + 16384);

        prep_kernel<<<256 + 8192 + 8192, 256, 0, stream>>>(
            x, gw, gb, usage, eidx, wgt, XB, w1, W1T, w2, W2T);
        build_lists<<<NE, 256, 0, stream>>>(
            eidx, wgt, cnt, tok_list, wt_list, tok2slot, wgt_p,
            done, offsets, usage, out_loss);
        gemm1_kernel<<<(D_FF / 128) * NE * (CAP / 128), 256, 0, stream>>>(
            XB, W1T, b1, cnt, offsets, tok_list, H);
        gemm2_y_kernel<<<2048, 256, 0, stream>>>(H, W2T, b2, cnt, offsets, Y);
        combine_kernel<<<NTOK, 256, 0, stream>>>(Y, tok2slot, wgt_p, offsets, out);
        return;
    }

    // fallback: sequential layout (WT reused for W1T then W2T)
    short* WT  = (short*)(w + 311424);
    short* H   = (short*)(w + 311424 + MB64);
    float* Y   = (float*)(w + 311424 + 2 * MB64);
    bool   use_y = ws_size >= need_y1;
    int*   eidx = (int*)WT;
    float* wgt  = (float*)(WT + NTOK * 2);

    router_kernel<<<256, 256, 0, stream>>>(x, gw, gb, usage, eidx, wgt, XB);
    build_lists<<<NE, 256, 0, stream>>>(
        eidx, wgt, cnt, tok_list, wt_list, tok2slot, wgt_p,
        done, offsets, usage, nullptr);

    transpose_cvt<<<dim3(D_FF / 64, D_MODEL / 64, NE), 256, 0, stream>>>(w1, WT, D_MODEL, D_FF);
    gemm1_kernel<<<(D_FF / 128) * NE * (CAP / 128), 256, 0, stream>>>(
        XB, WT, b1, cnt, offsets, tok_list, H);
    transpose_cvt<<<dim3(D_MODEL / 64, D_FF / 64, NE), 256, 0, stream>>>(w2, WT, D_FF, D_MODEL);

    if (use_y) {
        write_loss<<<1, 1, 0, stream>>>(usage, out_loss);
        gemm2_y_kernel<<<2048, 256, 0, stream>>>(H, WT, b2, cnt, offsets, Y);
        combine_kernel<<<NTOK, 256, 0, stream>>>(Y, tok2slot, wgt_p, offsets, out);
    } else {
        hipMemsetAsync(d_out, 0, (size_t)out_size * sizeof(float), stream);
        write_loss<<<1, 1, 0, stream>>>(usage, out_loss);
        gemm2_kernel<<<dim3(D_MODEL / 128, NE * (CAP / 128), 2), 256, 0, stream>>>(
            H, WT, b2, cnt, offsets, tok_list, wt_list, out);
    }
}